// Round 1
// baseline (161.372 us; speedup 1.0000x reference)
//
#include <hip/hip_runtime.h>
#include <math.h>

// NMI loss, shape (2,1,128,128,128) fp32.
// Exploits 2-sparsity of the soft histogram: PRETERM*(bin spacing)^2 = 50, so
// all but the two flanking bins carry weight <= exp(-50) ~ 2e-22 relative,
// utterly negligible vs the 2e-2 pass threshold. pa/pb are marginals of pab.

static constexpr int   V_PER_BATCH = 128 * 128 * 128;   // 2,097,152
static constexpr int   NBINS = 16;
static constexpr int   NB2   = NBINS * NBINS;           // 256
static constexpr float EPSF  = 1e-6f;
static constexpr int   HIST_BLOCKS = 512;               // per batch

// two-bin soft assignment: x -> bins k, k+1 with probs p0, p1
__device__ __forceinline__ void soft2(float x, int& k, float& p0, float& p1) {
    float t  = x * 15.0f;
    float kf = floorf(t);
    kf = fminf(fmaxf(kf, 0.0f), 14.0f);
    float f  = t - kf;
    float g  = 1.0f - f;
    float w0 = __expf(-50.0f * f * f);
    float w1 = __expf(-50.0f * g * g);
    float inv = 1.0f / (w0 + w1);
    p0 = w0 * inv;
    p1 = w1 * inv;
    k  = (int)kf;
}

__global__ __launch_bounds__(256) void nmi_hist(
        const float* __restrict__ ytrue,
        const float* __restrict__ ypred,
        float* __restrict__ ghist)        // [2][256], pre-zeroed
{
    __shared__ float hist[NB2];
    const int tid = threadIdx.x;
    hist[tid] = 0.0f;
    __syncthreads();

    const int batch = blockIdx.y;
    const float4* a4 = reinterpret_cast<const float4*>(ytrue + (size_t)batch * V_PER_BATCH);
    const float4* b4 = reinterpret_cast<const float4*>(ypred + (size_t)batch * V_PER_BATCH);
    const int n4     = V_PER_BATCH / 4;   // 524288
    const int stride = gridDim.x * blockDim.x;

    for (int i = blockIdx.x * blockDim.x + tid; i < n4; i += stride) {
        float4 av = a4[i];
        float4 bv = b4[i];
        const float ax[4] = {av.x, av.y, av.z, av.w};
        const float bx[4] = {bv.x, bv.y, bv.z, bv.w};
        #pragma unroll
        for (int e = 0; e < 4; ++e) {
            int ka, kb;
            float pa0, pa1, pb0, pb1;
            soft2(ax[e], ka, pa0, pa1);
            soft2(bx[e], kb, pb0, pb1);
            float* h = &hist[ka * NBINS + kb];
            atomicAdd(h,             pa0 * pb0);
            atomicAdd(h + 1,         pa0 * pb1);
            atomicAdd(h + NBINS,     pa1 * pb0);
            atomicAdd(h + NBINS + 1, pa1 * pb1);
        }
    }
    __syncthreads();
    atomicAdd(&ghist[batch * NB2 + tid], hist[tid]);
}

__global__ __launch_bounds__(256) void nmi_final(
        const float* __restrict__ ghist,  // [2][256] raw sums
        float* __restrict__ out)          // [2]
{
    const int b = blockIdx.x;
    const int t = threadIdx.x;
    __shared__ float pab[NB2];
    __shared__ float red[NB2];
    __shared__ float hx[NBINS], hy[NBINS];
    __shared__ float Hxy_s;

    const float invV = 1.0f / (float)V_PER_BATCH;
    float p = ghist[b * NB2 + t] * invV;
    pab[t] = p;
    red[t] = p * log2f(p + EPSF);
    __syncthreads();

    // block reduction of red -> sum
    for (int s = NB2 / 2; s > 0; s >>= 1) {
        if (t < s) red[t] += red[t + s];
        __syncthreads();
    }
    if (t == 0) Hxy_s = -red[0];

    // marginals
    if (t < NBINS) {
        float pa = 0.0f, pb = 0.0f;
        #pragma unroll
        for (int j = 0; j < NBINS; ++j) {
            pa += pab[t * NBINS + j];
            pb += pab[j * NBINS + t];
        }
        hx[t] = pa * log2f(pa + EPSF);
        hy[t] = pb * log2f(pb + EPSF);
    }
    __syncthreads();

    if (t == 0) {
        float Hx = 0.0f, Hy = 0.0f;
        #pragma unroll
        for (int i = 0; i < NBINS; ++i) { Hx += hx[i]; Hy += hy[i]; }
        Hx = -Hx; Hy = -Hy;
        float nmi = 2.0f * (1.0f - Hxy_s / (Hx + Hy));
        out[b] = 1.0f - nmi;
    }
}

extern "C" void kernel_launch(void* const* d_in, const int* in_sizes, int n_in,
                              void* d_out, int out_size, void* d_ws, size_t ws_size,
                              hipStream_t stream) {
    const float* ytrue = (const float*)d_in[0];
    const float* ypred = (const float*)d_in[1];
    float* out   = (float*)d_out;
    float* ghist = (float*)d_ws;          // 2*256 floats = 2 KB

    hipMemsetAsync(ghist, 0, 2 * NB2 * sizeof(float), stream);

    dim3 grid(HIST_BLOCKS, 2);
    nmi_hist<<<grid, 256, 0, stream>>>(ytrue, ypred, ghist);
    nmi_final<<<2, 256, 0, stream>>>(ghist, out);
}

// Round 2
// 160.534 us; speedup vs baseline: 1.0052x; 1.0052x over previous
//
#include <hip/hip_runtime.h>
#include <math.h>

// NMI loss, shape (2,1,128,128,128) fp32.
// R1 exact 2-sparse soft-hist passed (absmax 0.0) but LDS atomics with
// data-dependent bins cost ~218 cyc/wave-instr (random bank scatter).
// R2: bank-aligned column-replicated LDS hist: hist[bin][col], col=tid&31,
// so bank = tid&31 always -> 2 lanes/bank (free), all 4 per-voxel updates in
// the same column/bank. Per-block partials via plain stores (no memset, no
// global atomics); 2 dispatches total.

static constexpr int   V_PER_BATCH = 128 * 128 * 128;   // 2,097,152
static constexpr int   NBINS = 16;
static constexpr int   NB2   = NBINS * NBINS;           // 256
static constexpr float EPSF  = 1e-6f;
static constexpr int   BLOCKS_PER_BATCH = 256;          // ws = 2*256*256*4B = 512 KB
static constexpr int   NCOL  = 32;                      // column replicas (one per bank)

// two-bin soft assignment: x -> bins k, k+1 with probs p0, p1.
// PRETERM*(bin spacing)^2 = 50, third-nearest bin weight <= exp(-50): negligible.
__device__ __forceinline__ void soft2(float x, int& k, float& p0, float& p1) {
    float t  = x * 15.0f;
    float kf = floorf(t);
    kf = fminf(fmaxf(kf, 0.0f), 14.0f);
    float f  = t - kf;
    float g  = 1.0f - f;
    float w0 = __expf(-50.0f * f * f);
    float w1 = __expf(-50.0f * g * g);
    float inv = 1.0f / (w0 + w1);
    p0 = w0 * inv;
    p1 = w1 * inv;
    k  = (int)kf;
}

__global__ __launch_bounds__(256) void nmi_hist(
        const float* __restrict__ ytrue,
        const float* __restrict__ ypred,
        float* __restrict__ partial)      // [2][BLOCKS_PER_BATCH][256]
{
    __shared__ float hist[NB2 * NCOL];    // 32 KB, [bin][col]
    const int tid = threadIdx.x;
    const int col = tid & 31;

    // zero: addr word = c*256 + tid -> bank = tid%32, conflict-free
    #pragma unroll
    for (int c = 0; c < NCOL; ++c) hist[c * 256 + tid] = 0.0f;
    __syncthreads();

    const int batch = blockIdx.y;
    const float4* a4 = reinterpret_cast<const float4*>(ytrue + (size_t)batch * V_PER_BATCH);
    const float4* b4 = reinterpret_cast<const float4*>(ypred + (size_t)batch * V_PER_BATCH);

    const int stride = BLOCKS_PER_BATCH * 256;          // 65536
    const int i0     = blockIdx.x * 256 + tid;
    // n4 = 524288 = 8 * stride exactly
    #pragma unroll
    for (int it = 0; it < 8; ++it) {
        const int i = i0 + it * stride;
        float4 av = a4[i];
        float4 bv = b4[i];
        const float ax[4] = {av.x, av.y, av.z, av.w};
        const float bx[4] = {bv.x, bv.y, bv.z, bv.w};
        #pragma unroll
        for (int e = 0; e < 4; ++e) {
            int ka, kb;
            float pa0, pa1, pb0, pb1;
            soft2(ax[e], ka, pa0, pa1);
            soft2(bx[e], kb, pb0, pb1);
            float* h = &hist[(ka * NBINS + kb) * NCOL + col];
            atomicAdd(h,                 pa0 * pb0);   // (ka  , kb  )
            atomicAdd(h + NCOL,          pa0 * pb1);   // (ka  , kb+1)
            atomicAdd(h + NBINS * NCOL,  pa1 * pb0);   // (ka+1, kb  )
            atomicAdd(h + 17 * NCOL,     pa1 * pb1);   // (ka+1, kb+1)
        }
    }
    __syncthreads();

    // reduce 32 columns for bin=tid; rotate start column so bank=(c+tid)%32
    float s = 0.0f;
    #pragma unroll
    for (int c = 0; c < NCOL; ++c)
        s += hist[tid * NCOL + ((c + tid) & 31)];
    partial[((size_t)batch * BLOCKS_PER_BATCH + blockIdx.x) * NB2 + tid] = s;
}

__global__ __launch_bounds__(256) void nmi_final(
        const float* __restrict__ partial,  // [2][BLOCKS_PER_BATCH][256]
        float* __restrict__ out)            // [2]
{
    const int b = blockIdx.x;
    const int t = threadIdx.x;
    __shared__ float pab[NB2];
    __shared__ float red[NB2];
    __shared__ float hx[NBINS], hy[NBINS];
    __shared__ float Hxy_s;

    // sum this bin over all block partials (coalesced across t)
    const float* base = partial + (size_t)b * BLOCKS_PER_BATCH * NB2 + t;
    float s0 = 0.0f, s1 = 0.0f, s2 = 0.0f, s3 = 0.0f;
    #pragma unroll 4
    for (int blk = 0; blk < BLOCKS_PER_BATCH; blk += 4) {
        s0 += base[(size_t)(blk + 0) * NB2];
        s1 += base[(size_t)(blk + 1) * NB2];
        s2 += base[(size_t)(blk + 2) * NB2];
        s3 += base[(size_t)(blk + 3) * NB2];
    }
    const float invV = 1.0f / (float)V_PER_BATCH;
    float p = (s0 + s1 + s2 + s3) * invV;
    pab[t] = p;
    red[t] = p * log2f(p + EPSF);
    __syncthreads();

    for (int s = NB2 / 2; s > 0; s >>= 1) {
        if (t < s) red[t] += red[t + s];
        __syncthreads();
    }
    if (t == 0) Hxy_s = -red[0];

    if (t < NBINS) {
        float pa = 0.0f, pb = 0.0f;
        #pragma unroll
        for (int j = 0; j < NBINS; ++j) {
            pa += pab[t * NBINS + j];
            pb += pab[j * NBINS + t];
        }
        hx[t] = pa * log2f(pa + EPSF);
        hy[t] = pb * log2f(pb + EPSF);
    }
    __syncthreads();

    if (t == 0) {
        float Hx = 0.0f, Hy = 0.0f;
        #pragma unroll
        for (int i = 0; i < NBINS; ++i) { Hx += hx[i]; Hy += hy[i]; }
        Hx = -Hx; Hy = -Hy;
        float nmi = 2.0f * (1.0f - Hxy_s / (Hx + Hy));
        out[b] = 1.0f - nmi;
    }
}

extern "C" void kernel_launch(void* const* d_in, const int* in_sizes, int n_in,
                              void* d_out, int out_size, void* d_ws, size_t ws_size,
                              hipStream_t stream) {
    const float* ytrue = (const float*)d_in[0];
    const float* ypred = (const float*)d_in[1];
    float* out     = (float*)d_out;
    float* partial = (float*)d_ws;   // 512 KB used

    dim3 grid(BLOCKS_PER_BATCH, 2);
    nmi_hist<<<grid, 256, 0, stream>>>(ytrue, ypred, partial);
    nmi_final<<<2, 256, 0, stream>>>(partial, out);
}

// Round 3
// 152.116 us; speedup vs baseline: 1.0608x; 1.0553x over previous
//
#include <hip/hip_runtime.h>
#include <math.h>

// NMI loss, shape (2,1,128,128,128) fp32.
// R1/R2 showed fp32 LDS atomicAdd costs ~206 cyc/wave-instr regardless of
// banking (likely CAS-loop lowering). R3: fixed-point (2^20) integer
// ds_add_u32 into bank-aligned column-replicated hist[bin][col], col=tid&31
// (2 lanes/bank = free). Block partials accumulate exactly into global u64
// fixed-point hist via device-scope atomics; last-finished block computes the
// entropies (single fused kernel + one 4KB memset node).

static constexpr int   V_PER_BATCH = 128 * 128 * 128;   // 2,097,152
static constexpr int   NBINS = 16;
static constexpr int   NB2   = 256;
static constexpr int   NCOL  = 32;                      // one replica column per bank
static constexpr int   BPB   = 512;                     // blocks per batch
static constexpr int   TOTAL_BLOCKS = BPB * 2;          // 1024 -> 4 blocks/CU
static constexpr float EPSF  = 1e-6f;
static constexpr float SCALE = 1048576.0f;              // 2^20
static constexpr float INV_SCALE = 1.0f / 1048576.0f;

// two-bin soft assignment. PRETERM*(spacing)^2 = 50 => third bin <= exp(-50),
// negligible. p0 = w0/(w0+w1) = 1/(1+exp(100f-50)) = 1/(1+exp2(144.27*(f-.5)))
__device__ __forceinline__ void soft2(float x, int& k, float& p0, float& p1) {
    float t  = x * 15.0f;
    float kf = floorf(t);
    kf = fminf(fmaxf(kf, 0.0f), 14.0f);   // guard x==1.0 edge (OOB otherwise)
    float f  = t - kf;
    float e  = __builtin_exp2f(144.269504089f * (f - 0.5f));
    p0 = __builtin_amdgcn_rcpf(1.0f + e);
    p1 = 1.0f - p0;
    k  = (int)kf;
}

__global__ __launch_bounds__(256) void nmi_fused(
        const float* __restrict__ ytrue,
        const float* __restrict__ ypred,
        unsigned long long* __restrict__ ghist,   // [2][256] fixed-point, zeroed
        unsigned int* __restrict__ counter,       // [1], zeroed
        float* __restrict__ out)                  // [2]
{
    __shared__ unsigned int hist[NB2 * NCOL];     // 32 KB, [bin][col]
    const int tid = threadIdx.x;
    const int col = tid & 31;

    #pragma unroll
    for (int c = 0; c < NCOL; ++c) hist[c * 256 + tid] = 0u;
    __syncthreads();

    const int batch = blockIdx.y;
    const float4* a4 = reinterpret_cast<const float4*>(ytrue + (size_t)batch * V_PER_BATCH);
    const float4* b4 = reinterpret_cast<const float4*>(ypred + (size_t)batch * V_PER_BATCH);

    const int stride = BPB * 256;                 // 131072
    const int i0     = blockIdx.x * 256 + tid;
    // n4 = 524288 = 4 * stride exactly
    #pragma unroll
    for (int it = 0; it < 4; ++it) {
        const int i = i0 + it * stride;
        float4 av = a4[i];
        float4 bv = b4[i];
        const float ax[4] = {av.x, av.y, av.z, av.w};
        const float bx[4] = {bv.x, bv.y, bv.z, bv.w};
        #pragma unroll
        for (int e = 0; e < 4; ++e) {
            int ka, kb;
            float pa0, pa1, pb0, pb1;
            soft2(ax[e], ka, pa0, pa1);
            soft2(bx[e], kb, pb0, pb1);
            float pa0s = pa0 * SCALE, pa1s = pa1 * SCALE;
            unsigned q00 = (unsigned)(pa0s * pb0);
            unsigned q01 = (unsigned)(pa0s * pb1);
            unsigned q10 = (unsigned)(pa1s * pb0);
            unsigned q11 = (unsigned)(pa1s * pb1);
            unsigned base = (unsigned)((ka * NBINS + kb) * NCOL + col);
            atomicAdd(&hist[base],             q00);   // (ka  , kb  )
            atomicAdd(&hist[base + NCOL],      q01);   // (ka  , kb+1)
            atomicAdd(&hist[base + 16 * NCOL], q10);   // (ka+1, kb  )
            atomicAdd(&hist[base + 17 * NCOL], q11);   // (ka+1, kb+1)
        }
    }
    __syncthreads();

    // exact integer column-reduce for bin=tid; rotate start column: bank=(c+tid)%32
    unsigned long long s = 0ull;
    #pragma unroll
    for (int c = 0; c < NCOL; ++c)
        s += (unsigned long long)hist[tid * NCOL + ((c + tid) & 31)];
    atomicAdd(&ghist[batch * NB2 + tid], s);          // device-scope u64

    // last-block-done: only the final arriver computes the entropies
    __threadfence();                                   // ghist adds visible before inc
    __shared__ int is_last;
    if (tid == 0) {
        unsigned prev = atomicAdd(counter, 1u);
        is_last = (prev == (unsigned)(TOTAL_BLOCKS - 1));
    }
    __syncthreads();
    if (!is_last) return;
    __threadfence();                                   // acquire side

    __shared__ float pab[NB2];
    __shared__ float red[NB2];
    __shared__ float hx[NBINS], hy[NBINS];
    const float toP = INV_SCALE / (float)V_PER_BATCH;

    for (int b = 0; b < 2; ++b) {
        unsigned long long v = __hip_atomic_load(&ghist[b * NB2 + tid],
                                                 __ATOMIC_RELAXED,
                                                 __HIP_MEMORY_SCOPE_AGENT);
        float p = (float)v * toP;
        pab[tid] = p;
        red[tid] = p * log2f(p + EPSF);
        __syncthreads();

        for (int sft = NB2 / 2; sft > 0; sft >>= 1) {
            if (tid < sft) red[tid] += red[tid + sft];
            __syncthreads();
        }
        // red[0] = sum p log2(p+eps), synced for all threads

        if (tid < NBINS) {
            float pa = 0.0f, pb = 0.0f;
            #pragma unroll
            for (int j = 0; j < NBINS; ++j) {
                pa += pab[tid * NBINS + j];
                pb += pab[j * NBINS + tid];
            }
            hx[tid] = pa * log2f(pa + EPSF);
            hy[tid] = pb * log2f(pb + EPSF);
        }
        __syncthreads();

        if (tid == 0) {
            float Hxy = -red[0];
            float Hx = 0.0f, Hy = 0.0f;
            #pragma unroll
            for (int i = 0; i < NBINS; ++i) { Hx += hx[i]; Hy += hy[i]; }
            Hx = -Hx; Hy = -Hy;
            float nmi = 2.0f * (1.0f - Hxy / (Hx + Hy));
            out[b] = 1.0f - nmi;
        }
        __syncthreads();   // protect pab/red before next batch iteration
    }
}

extern "C" void kernel_launch(void* const* d_in, const int* in_sizes, int n_in,
                              void* d_out, int out_size, void* d_ws, size_t ws_size,
                              hipStream_t stream) {
    const float* ytrue = (const float*)d_in[0];
    const float* ypred = (const float*)d_in[1];
    float* out = (float*)d_out;

    unsigned long long* ghist = (unsigned long long*)d_ws;         // 512 * 8B = 4 KB
    unsigned int* counter = (unsigned int*)((char*)d_ws + 4096);   // 4 B

    hipMemsetAsync(d_ws, 0, 4096 + 64, stream);

    dim3 grid(BPB, 2);
    nmi_fused<<<grid, 256, 0, stream>>>(ytrue, ypred, ghist, counter, out);
}

// Round 4
// 107.631 us; speedup vs baseline: 1.4993x; 1.4133x over previous
//
#include <hip/hip_runtime.h>
#include <math.h>

// NMI loss, shape (2,1,128,128,128) fp32.
// R1-R3 measured: LDS *atomics* (fp32 or u32, bank-aligned or not) cost
// ~3.2 cyc/lane of LDS-unit time -> 87us floor. R4 removes atomics:
// per-lane PRIVATE u16 histograms, hist[bin][lane] (lane owns its column,
// plain read-modify-write is race-free; bank = lane%32 = 2 lanes/bank, free).
// Scale 2^8, 64 voxels/lane -> max entry 16384, no overflow. 64-thread
// blocks, 32KB LDS -> 4 waves/CU. Exact u32 block sums -> global u32
// fixed-point hist; last-finished block computes entropies.

static constexpr int   V_PER_BATCH = 128 * 128 * 128;   // 2,097,152
static constexpr int   NBINS = 16;
static constexpr int   NB2   = 256;
static constexpr int   BPB   = 512;                     // 64-thread blocks per batch
static constexpr int   TOTAL_BLOCKS = BPB * 2;          // 1024 -> 4 waves/CU
static constexpr float EPSF  = 1e-6f;
static constexpr float SCALE = 256.0f;                  // per-voxel fixed point

// two-bin soft assignment. PRETERM*(spacing)^2 = 50 => third bin <= exp(-50),
// negligible. p0 = 1/(1+exp(100f-50)) = 1/(1+exp2(144.27*(f-0.5)))
__device__ __forceinline__ void soft2(float x, int& k, float& p0, float& p1) {
    float t  = x * 15.0f;
    float kf = floorf(t);
    kf = fminf(fmaxf(kf, 0.0f), 14.0f);
    float f  = t - kf;
    float e  = __builtin_exp2f(144.269504089f * (f - 0.5f));
    p0 = __builtin_amdgcn_rcpf(1.0f + e);
    p1 = 1.0f - p0;
    k  = (int)kf;
}

__global__ __launch_bounds__(64) void nmi_fused(
        const float* __restrict__ ytrue,
        const float* __restrict__ ypred,
        unsigned int* __restrict__ ghist,    // [2][256] fixed-point, zeroed
        unsigned int* __restrict__ counter,  // [1], zeroed
        float* __restrict__ out)             // [2]
{
    __shared__ unsigned short hist[NB2 * 64];   // 32 KB, [bin][lane]
    const int tid = threadIdx.x;

    // zero 32KB: 2048 uint4 stores / 64 lanes = 32 per lane
    uint4* h128 = reinterpret_cast<uint4*>(hist);
    #pragma unroll
    for (int j = 0; j < 32; ++j) {
        h128[j * 64 + tid] = make_uint4(0u, 0u, 0u, 0u);
    }
    __syncthreads();

    const int batch = blockIdx.y;
    const float4* a4 = reinterpret_cast<const float4*>(ytrue + (size_t)batch * V_PER_BATCH);
    const float4* b4 = reinterpret_cast<const float4*>(ypred + (size_t)batch * V_PER_BATCH);

    // n4 = 524288 = 16 * (BPB*64); 16 iters x 4 voxels = 64 voxels/lane
    int i = blockIdx.x * 64 + tid;
    #pragma unroll
    for (int it = 0; it < 16; ++it, i += BPB * 64) {
        float4 av = a4[i];
        float4 bv = b4[i];
        const float ax[4] = {av.x, av.y, av.z, av.w};
        const float bx[4] = {bv.x, bv.y, bv.z, bv.w};
        #pragma unroll
        for (int e = 0; e < 4; ++e) {
            int ka, kb;
            float pa0, pa1, pb0, pb1;
            soft2(ax[e], ka, pa0, pa1);
            soft2(bx[e], kb, pb0, pb1);
            float s0 = pa0 * SCALE, s1 = pa1 * SCALE;
            unsigned q00 = (unsigned)(s0 * pb0 + 0.5f);
            unsigned q01 = (unsigned)(s0 * pb1 + 0.5f);
            unsigned q10 = (unsigned)(s1 * pb0 + 0.5f);
            unsigned q11 = (unsigned)(s1 * pb1 + 0.5f);
            int base = (ka * NBINS + kb) * 64 + tid;
            // plain per-lane RMW: lane owns column tid, no races, no conflicts
            hist[base]        = (unsigned short)(hist[base]        + q00); // (ka  ,kb  )
            hist[base + 64]   = (unsigned short)(hist[base + 64]   + q01); // (ka  ,kb+1)
            hist[base + 1024] = (unsigned short)(hist[base + 1024] + q10); // (ka+1,kb  )
            hist[base + 1088] = (unsigned short)(hist[base + 1088] + q11); // (ka+1,kb+1)
        }
    }
    __syncthreads();

    // block reduce: thread t sums bins {t, t+64, t+128, t+192} over 64 lanes
    // (32 u32 words each, rotated start -> bank (j+t)%32, conflict-free)
    const unsigned int* h32 = reinterpret_cast<const unsigned int*>(hist);
    #pragma unroll
    for (int r = 0; r < 4; ++r) {
        const int bin = tid + r * 64;
        unsigned sum = 0;
        #pragma unroll
        for (int j = 0; j < 32; ++j) {
            unsigned v = h32[bin * 32 + ((j + tid) & 31)];
            sum += (v & 0xFFFFu) + (v >> 16);
        }
        atomicAdd(&ghist[batch * NB2 + bin], sum);   // device-scope u32, exact
    }

    // last-block-done: final arriver computes entropies
    __threadfence();
    __shared__ int is_last;
    if (tid == 0) {
        unsigned prev = atomicAdd(counter, 1u);
        is_last = (prev == (unsigned)(TOTAL_BLOCKS - 1));
    }
    __syncthreads();
    if (!is_last) return;
    __threadfence();

    __shared__ float pab[NB2];
    __shared__ float red[64];
    __shared__ float hx[NBINS], hy[NBINS];
    const float toP = 1.0f / (SCALE * (float)V_PER_BATCH);

    for (int b = 0; b < 2; ++b) {
        float rsum = 0.0f;
        #pragma unroll
        for (int r = 0; r < 4; ++r) {
            const int bin = tid + r * 64;
            unsigned v = __hip_atomic_load(&ghist[b * NB2 + bin],
                                           __ATOMIC_RELAXED,
                                           __HIP_MEMORY_SCOPE_AGENT);
            float p = (float)v * toP;
            pab[bin] = p;
            rsum += p * log2f(p + EPSF);
        }
        red[tid] = rsum;
        __syncthreads();
        for (int s = 32; s > 0; s >>= 1) {
            if (tid < s) red[tid] += red[tid + s];
            __syncthreads();
        }

        if (tid < NBINS) {
            float pa = 0.0f, pb = 0.0f;
            #pragma unroll
            for (int j = 0; j < NBINS; ++j) {
                pa += pab[tid * NBINS + j];
                pb += pab[j * NBINS + tid];
            }
            hx[tid] = pa * log2f(pa + EPSF);
            hy[tid] = pb * log2f(pb + EPSF);
        }
        __syncthreads();

        if (tid == 0) {
            float Hxy = -red[0];
            float Hx = 0.0f, Hy = 0.0f;
            #pragma unroll
            for (int i2 = 0; i2 < NBINS; ++i2) { Hx += hx[i2]; Hy += hy[i2]; }
            Hx = -Hx; Hy = -Hy;
            float nmi = 2.0f * (1.0f - Hxy / (Hx + Hy));
            out[b] = 1.0f - nmi;
        }
        __syncthreads();
    }
}

extern "C" void kernel_launch(void* const* d_in, const int* in_sizes, int n_in,
                              void* d_out, int out_size, void* d_ws, size_t ws_size,
                              hipStream_t stream) {
    const float* ytrue = (const float*)d_in[0];
    const float* ypred = (const float*)d_in[1];
    float* out = (float*)d_out;

    unsigned int* ghist   = (unsigned int*)d_ws;                  // 512 * 4B = 2 KB
    unsigned int* counter = (unsigned int*)((char*)d_ws + 4096);  // 4 B

    hipMemsetAsync(d_ws, 0, 4096 + 64, stream);

    dim3 grid(BPB, 2);
    nmi_fused<<<grid, 64, 0, stream>>>(ytrue, ypred, ghist, counter, out);
}